// Round 1
// baseline (132.901 us; speedup 1.0000x reference)
//
#include <hip/hip_runtime.h>
#include <stdint.h>

#define HIDDEN 4096
#define MAX_N  100

// ---------------------------------------------------------------------------
// Threefry2x32, 20 rounds, exactly as in jax/_src/prng.py.
// key schedule: ks = [A, B, C=A^B^0x1BD11BDA]; x0+=A, x1+=B up front, then
// 5 groups of 4 rounds with rotation sets {13,15,26,6} / {17,29,16,24}
// alternating, key injection + round counter after each group.
// ---------------------------------------------------------------------------
__device__ __forceinline__ uint32_t rotl32(uint32_t x, int d) {
    return (x << d) | (x >> (32 - d));
}

__device__ __forceinline__ void tf_block(uint32_t A, uint32_t B,
                                         uint32_t x0, uint32_t x1,
                                         uint32_t& o0, uint32_t& o1) {
    const uint32_t C = A ^ B ^ 0x1BD11BDAu;
    x0 += A; x1 += B;
#define TF_G(r0, r1, r2, r3)                 \
    x0 += x1; x1 = rotl32(x1, r0) ^ x0;      \
    x0 += x1; x1 = rotl32(x1, r1) ^ x0;      \
    x0 += x1; x1 = rotl32(x1, r2) ^ x0;      \
    x0 += x1; x1 = rotl32(x1, r3) ^ x0;
    TF_G(13, 15, 26, 6);  x0 += B; x1 += C + 1u;
    TF_G(17, 29, 16, 24); x0 += C; x1 += A + 2u;
    TF_G(13, 15, 26, 6);  x0 += A; x1 += B + 3u;
    TF_G(17, 29, 16, 24); x0 += B; x1 += C + 4u;
    TF_G(13, 15, 26, 6);  x0 += C; x1 += A + 5u;
#undef TF_G
    o0 = x0; o1 = x1;
}

// partitionable random_bits(key, 32, (n,)): bits[i] = o0 ^ o1 of block (0, i)
__device__ __forceinline__ int sample_keep(uint32_t k0, uint32_t k1, int h) {
    uint32_t o0, o1;
    tf_block(k0, k1, 0u, (uint32_t)h, o0, o1);
    uint32_t bits = o0 ^ o1;
    float u = __uint_as_float((bits >> 9) | 0x3F800000u) - 1.0f;
    return (u >= 0.9f) ? 1 : 0;   // keep with prob 1-P, P=0.9
}

// ---------------------------------------------------------------------------
// Kernel A: replicate _accumulate_masks(4096, f32) exactly; write
// scale[h] = sum_mask[h] / i into d_ws (4096 floats). Single block.
// ---------------------------------------------------------------------------
__global__ void __launch_bounds__(256)
mask_kernel(float* __restrict__ scale) {
    __shared__ int s_sum[HIDDEN];
    __shared__ int s_count;
    const int tid = threadIdx.x;

    // key = jax.random.key(42) -> (hi, lo) = (0, 42)
    uint32_t kA = 0u, kB = 42u;
    uint32_t sk0, sk1;

    // key, k0 = split(key)   (fold-like: child j = TF(key, 0, j))
    {
        uint32_t a0, a1, b0, b1;
        tf_block(kA, kB, 0u, 0u, a0, a1);
        tf_block(kA, kB, 0u, 1u, b0, b1);
        kA = a0; kB = a1; sk0 = b0; sk1 = b1;
    }

    if (tid == 0) s_count = 0;
    int local = 0;
    for (int h = tid; h < HIDDEN; h += 256) {
        int m = sample_keep(sk0, sk1, h);
        s_sum[h] = m;
        local += m;
    }
    __syncthreads();
    atomicAdd(&s_count, local);
    __syncthreads();

    int i = 1;
    int count = s_count;

    // while i < 100 and mean(sum != 0) < 0.4  (f32-exact: count/4096 < 0.4f)
    while (i < MAX_N && ((float)count / 4096.0f) < 0.4f) {
        // key, k = split(key)
        uint32_t a0, a1, b0, b1;
        tf_block(kA, kB, 0u, 0u, a0, a1);
        tf_block(kA, kB, 0u, 1u, b0, b1);
        kA = a0; kB = a1; sk0 = b0; sk1 = b1;

        __syncthreads();
        if (tid == 0) s_count = 0;
        __syncthreads();

        local = 0;
        for (int h = tid; h < HIDDEN; h += 256) {
            int v = s_sum[h] + sample_keep(sk0, sk1, h);
            s_sum[h] = v;
            local += (v != 0) ? 1 : 0;
        }
        atomicAdd(&s_count, local);
        __syncthreads();
        count = s_count;
        ++i;
    }

    const float fi = (float)i;
    for (int h = tid; h < HIDDEN; h += 256) {
        scale[h] = (float)s_sum[h] / fi;
    }
}

// ---------------------------------------------------------------------------
// Kernel B: out = x * scale[h], float4 grid-stride. Row length 4096 f32 =
// 1024 float4, so the per-element scale index is (idx & 1023).
// ---------------------------------------------------------------------------
__global__ void __launch_bounds__(256)
scale_kernel(const float4* __restrict__ x, const float* __restrict__ scale,
             float4* __restrict__ out, int n4) {
    const float4* s4 = reinterpret_cast<const float4*>(scale);
    const int stride = gridDim.x * blockDim.x;
    for (int idx = blockIdx.x * blockDim.x + threadIdx.x; idx < n4; idx += stride) {
        float4 s = s4[idx & 1023];
        float4 v = x[idx];
        v.x *= s.x; v.y *= s.y; v.z *= s.z; v.w *= s.w;
        out[idx] = v;
    }
}

extern "C" void kernel_launch(void* const* d_in, const int* in_sizes, int n_in,
                              void* d_out, int out_size, void* d_ws, size_t ws_size,
                              hipStream_t stream) {
    const float* x = (const float*)d_in[0];
    float* out = (float*)d_out;
    float* scale = (float*)d_ws;   // 4096 floats = 16 KB scratch

    mask_kernel<<<1, 256, 0, stream>>>(scale);

    const int n4 = out_size / 4;   // 67108864 / 4 = 16777216 float4
    scale_kernel<<<2048, 256, 0, stream>>>(
        reinterpret_cast<const float4*>(x), scale,
        reinterpret_cast<float4*>(out), n4);
}